// Round 9
// baseline (291.673 us; speedup 1.0000x reference)
//
#include <hip/hip_runtime.h>
#include <math.h>

// N=100000 nodes, D=128 feats, E=1600000 edges.
// f = alpha*(Ax - x) + beta*(-(x-1)*x) + clip(src*x0,-1,1)*0.1,  Ax[row] += w*x[col]
//
// R11: build occupancy fix #2.
//  - place: EPB 2048 -> 782 blocks (3/CU; R10's 196 blocks left 60 CUs idle).
//    Transposed directory dir[b*nBlk+blk] ((lexcl<<12)|len) -> sort reads coalesced.
//  - sort: per-CHUNK copy-in loop (thread->chunk, ~2.6 contiguous records) replaces
//    per-RECORD 8-deep LDS binary search. Chunk prefix via 4-wide scan of dir row.
//  - gather: R10 bf16 kernel unchanged (measured 88us, FETCH 288MB).
//  - cvt: unchanged wide kernel; zeroes cursors.

#define D_FEAT 128
#define RPB 128             // rows per bucket -> NB = 782
#define NB_MAX 800
#define SORT_CAP 2560       // records per bucket (mean 2048, sd ~45; 11 sigma)
#define EPB 2048            // edges per place block (256 thr x 8)
#define EPT 8
#define NBLK_MAX 800        // sort supports <=800 place blocks (782 here)

__device__ __forceinline__ float sigmoid_f(float v) {
    return 1.0f / (1.0f + __expf(-v));
}

__device__ __forceinline__ unsigned bf16rn(float f) {   // RNE f32->bf16 (bits)
    unsigned u = __float_as_uint(f);
    return (u + 0x7FFFu + ((u >> 16) & 1u)) >> 16;
}

// x (f32) -> xb (bf16), 8 floats/thread; block 0 thread 0 zeroes cursors.
__global__ __launch_bounds__(256) void cvt_kernel(const float* __restrict__ x,
                                                  unsigned short* __restrict__ xb,
                                                  int n8, int* __restrict__ cursors) {
    int i = blockIdx.x * 256 + threadIdx.x;
    if (blockIdx.x == 0 && threadIdx.x == 0) { cursors[0] = 0; cursors[1] = 0; }
    if (!xb || i >= n8) return;
    const float4* x4 = (const float4*)x;
    float4 f0 = x4[(size_t)i * 2];
    float4 f1 = x4[(size_t)i * 2 + 1];
    uint4 o;
    o.x = bf16rn(f0.x) | (bf16rn(f0.y) << 16);
    o.y = bf16rn(f0.z) | (bf16rn(f0.w) << 16);
    o.z = bf16rn(f1.x) | (bf16rn(f1.y) << 16);
    o.w = bf16rn(f1.z) | (bf16rn(f1.w) << 16);
    ((uint4*)xb)[i] = o;
}

// Chunked-arena placement, 2048 edges/block (782 blocks, ~3/CU).
// Per block: LDS hist over NB buckets, block scan, ONE global atomic reserves
// the block's arena range, direct global scatter at gbase+lexcl[bkt]+rank.
// Directory row (transposed): dir[b*nBlk + blk] = (lexcl<<12)|len.
__global__ __launch_bounds__(256) void place_kernel(const int* __restrict__ rows,
                                                    const int* __restrict__ cols,
                                                    const float* __restrict__ w,
                                                    const float* __restrict__ alpha_p,
                                                    int* __restrict__ arenaCur,
                                                    int2* __restrict__ arena,
                                                    unsigned* __restrict__ dir,
                                                    int* __restrict__ blkBase,
                                                    int E, int NB, int nBlk) {
    __shared__ int hist[NB_MAX];        // counts, then scatter cursor
    __shared__ int lexcl[NB_MAX];
    __shared__ int scanb[256];
    __shared__ int gbase_sh;
    int t = threadIdx.x;
    int blk = blockIdx.x;
    int base = blk * EPB;
    for (int i = t; i < NB; i += 256) hist[i] = 0;
    __syncthreads();

    // phase 1: stage row ids in registers, then count
    int rr[EPT];
#pragma unroll
    for (int k = 0; k < EPT; ++k) {
        int e = base + k * 256 + t;
        rr[k] = (e < E) ? rows[e] : -1;
    }
#pragma unroll
    for (int k = 0; k < EPT; ++k)
        if (rr[k] >= 0) atomicAdd(&hist[rr[k] >> 7], 1);
    __syncthreads();

    // phase 2: block scan hist -> lexcl (4/thread + H-S over 256 partials)
    const int CHK = 4;                  // 256*4 = 1024 >= NB_MAX
    int loc[CHK];
    int run = 0;
#pragma unroll
    for (int k = 0; k < CHK; ++k) {
        int idx = t * CHK + k;
        int v = (idx < NB) ? hist[idx] : 0;
        loc[k] = run; run += v;
    }
    scanb[t] = run;
    __syncthreads();
    for (int d = 1; d < 256; d <<= 1) {
        int tv = (t >= d) ? scanb[t - d] : 0;
        __syncthreads();
        scanb[t] += tv;
        __syncthreads();
    }
    int excl = scanb[t] - run;
    int total = scanb[255];
#pragma unroll
    for (int k = 0; k < CHK; ++k) {
        int idx = t * CHK + k;
        if (idx < NB) lexcl[idx] = excl + loc[k];
    }
    if (t == 0) gbase_sh = atomicAdd(arenaCur, total);
    __syncthreads();
    for (int i = t; i < NB; i += 256) hist[i] = lexcl[i];   // cursors
    __syncthreads();
    int gbase = gbase_sh;
    const float alpha = sigmoid_f(alpha_p[0]) * 0.1f;

    // phase 3: direct global scatter, cols/w register-staged
    int   cc[EPT];
    float wwv[EPT];
#pragma unroll
    for (int k = 0; k < EPT; ++k) {
        int e = base + k * 256 + t;
        cc[k]  = (e < E) ? cols[e] : 0;
        wwv[k] = (e < E) ? w[e]    : 0.0f;
    }
#pragma unroll
    for (int k = 0; k < EPT; ++k) {
        int r = rr[k];
        if (r < 0) continue;
        int bkt = r >> 7;
        int pos = atomicAdd(&hist[bkt], 1);   // local (lexcl-based) rank
        arena[gbase + pos] = make_int2(((r & 127) << 17) | cc[k],
                                       __float_as_int(wwv[k] * alpha));
    }
    __syncthreads();

    // directory (transposed: coalesced for sort) + block base
    for (int b = t; b < NB; b += 256) {
        int le  = lexcl[b];
        int len = ((b + 1 < NB) ? lexcl[b + 1] : total) - le;
        dir[(size_t)b * nBlk + blk] = ((unsigned)le << 12) | (unsigned)len;
    }
    if (t == 0) blkBase[blk] = gbase;
}

// Block-per-bucket: scan the (coalesced) directory row -> chunk prefix,
// per-CHUNK copy-in (no per-record search), LDS counting sort by row-local id,
// ONE atomic reserves output region, coalesced 4B-packed flush.
// Packed col_w record: (bf16(w*alpha)&0x7FFF) << 17 | col   (w*alpha >= 0).
__global__ __launch_bounds__(256) void sort_kernel(const int2* __restrict__ arena,
                                                   const unsigned* __restrict__ dir,
                                                   const int* __restrict__ blkBase,
                                                   int nBlk,
                                                   unsigned* __restrict__ col_w,
                                                   int* __restrict__ outCur,
                                                   int* __restrict__ off,
                                                   int* __restrict__ bstart2,
                                                   int N, int NB) {
    __shared__ int2 sbuf[SORT_CAP];         // 20 KiB
    __shared__ unsigned obuf[SORT_CAP];     // 10 KiB
    __shared__ int pre[NBLK_MAX + 1];       // 3.2 KiB
    __shared__ int abase[NBLK_MAX];         // 3.2 KiB
    __shared__ int scanb[256];
    __shared__ int hist[RPB];
    __shared__ int hscan[RPB];
    __shared__ int cursor[RPB];
    __shared__ int gb_sh;
    int b = blockIdx.x;
    int t = threadIdx.x;

    // chunk descriptors: 4 consecutive per thread (coalesced dir reads), scan
    const int CHK = 4;                      // 256*4 = 1024 >= NBLK_MAX
    int lloc[CHK];
    int run = 0;
#pragma unroll
    for (int k = 0; k < CHK; ++k) {
        int c = t * CHK + k;
        int len = 0;
        if (c < nBlk) {
            unsigned d = dir[(size_t)b * nBlk + c];
            len = (int)(d & 0xFFFu);
            abase[c] = blkBase[c] + (int)(d >> 12);
        }
        lloc[k] = run; run += len;
    }
    scanb[t] = run;
    __syncthreads();
    for (int d = 1; d < 256; d <<= 1) {
        int tv = (t >= d) ? scanb[t - d] : 0;
        __syncthreads();
        scanb[t] += tv;
        __syncthreads();
    }
    int excl = scanb[t] - run;
#pragma unroll
    for (int k = 0; k < CHK; ++k) {
        int c = t * CHK + k;
        if (c < nBlk) pre[c] = excl + lloc[k];
    }
    if (t == 0) {
        int total = scanb[255];
        pre[nBlk] = total;
        gb_sh = atomicAdd(outCur, total);
    }
    if (t < RPB) hist[t] = 0;
    __syncthreads();
    int cntb  = pre[nBlk];
    int gbase = gb_sh;
    bool fast = (cntb <= SORT_CAP);

    // per-chunk copy-in + row hist (thread -> chunk; ~2-3 contiguous records)
    for (int c = t; c < nBlk; c += 256) {
        int p = pre[c];
        int n = pre[c + 1] - p;
        int a = abase[c];
        for (int k = 0; k < n; ++k) {
            int2 rec = arena[a + k];
            if (fast) sbuf[p + k] = rec;
            atomicAdd(&hist[rec.x >> 17], 1);
        }
    }
    __syncthreads();

    // scan 128 row counts
    int v = 0;
    if (t < RPB) { v = hist[t]; hscan[t] = v; }
    __syncthreads();
    for (int d = 1; d < RPB; d <<= 1) {
        int tv = (t >= d && t < RPB) ? hscan[t - d] : 0;
        __syncthreads();
        if (t < RPB) hscan[t] += tv;
        __syncthreads();
    }
    if (t < RPB) {
        int incl = hscan[t];
        int ex2  = incl - v;
        int row = b * RPB + t;
        if (row < N) off[row] = gbase + incl;    // END; start via off[row-1]/bstart2
        cursor[t] = fast ? ex2 : (gbase + ex2);
    }
    if (t == 0) bstart2[b] = gbase;
    __syncthreads();

    if (fast) {
        for (int i = t; i < cntb; i += 256) {
            int2 r = sbuf[i];
            int rl = r.x >> 17;
            int pos = atomicAdd(&cursor[rl], 1);
            unsigned wb = bf16rn(__int_as_float(r.y)) & 0x7FFFu;
            obuf[pos] = (wb << 17) | (unsigned)(r.x & 0x1FFFF);
        }
        __syncthreads();
        for (int i = t; i < cntb; i += 256)      // coalesced flush
            col_w[gbase + i] = obuf[i];
    } else {
        for (int c = t; c < nBlk; c += 256) {
            int p = pre[c];
            int n = pre[c + 1] - p;
            int a = abase[c];
            for (int k = 0; k < n; ++k) {
                int2 r = arena[a + k];
                int rl = r.x >> 17;
                int pos = atomicAdd(&cursor[rl], 1);
                unsigned wb = bf16rn(__int_as_float(r.y)) & 0x7FFFu;
                col_w[pos] = (wb << 17) | (unsigned)(r.x & 0x1FFFF);
            }
        }
    }
}

// bf16 gather: one 64-lane wave per row, half-wave per edge, unroll 4.
// [R10, measured 88us] 4B packed col_w:
//   col = p & 0x1FFFF;  w = as_float((p >> 17) << 16)   (sign bit 0).
__global__ void gather_bf16_kernel(const float* __restrict__ x,
                                   const unsigned short* __restrict__ xb,
                                   const float* __restrict__ x0,
                                   const int* __restrict__ off,
                                   const int* __restrict__ bstart2,
                                   const unsigned* __restrict__ col_w,
                                   const float* __restrict__ alpha_p,
                                   const float* __restrict__ beta_p,
                                   const float* __restrict__ src_p,
                                   float* __restrict__ out, int N) {
    const float alpha = sigmoid_f(alpha_p[0]) * 0.1f;
    const float beta  = sigmoid_f(beta_p[0]) * 0.1f;
    const float src   = src_p[0];

    int gtid = blockIdx.x * blockDim.x + threadIdx.x;
    int row  = gtid >> 6;
    if (row >= N) return;
    int lane  = threadIdx.x & 63;
    int half  = lane >> 5;
    int flane = lane & 31;

    int start = ((row & 127) == 0) ? bstart2[row >> 7] : off[row - 1];
    int end   = off[row];

    const uint2* xb2 = (const uint2*)xb;   // 32 uint2 per row
    float4 a0 = make_float4(0.f, 0.f, 0.f, 0.f);
    float4 a1 = make_float4(0.f, 0.f, 0.f, 0.f);
    float4 a2 = make_float4(0.f, 0.f, 0.f, 0.f);
    float4 a3 = make_float4(0.f, 0.f, 0.f, 0.f);

#define BF16_FMA(ACC, V, W)                                                    \
    {                                                                          \
        float b0 = __uint_as_float((V).x << 16);                               \
        float b1 = __uint_as_float((V).x & 0xFFFF0000u);                       \
        float b2 = __uint_as_float((V).y << 16);                               \
        float b3 = __uint_as_float((V).y & 0xFFFF0000u);                       \
        ACC.x += (W) * b0; ACC.y += (W) * b1;                                  \
        ACC.z += (W) * b2; ACC.w += (W) * b3;                                  \
    }
#define UNPACK_W(P) __uint_as_float(((P) >> 17) << 16)

    int j = start + half;
    for (; j + 6 < end; j += 8) {
        unsigned p0 = col_w[j];
        unsigned p1 = col_w[j + 2];
        unsigned p2 = col_w[j + 4];
        unsigned p3 = col_w[j + 6];
        uint2 v0 = xb2[(size_t)(p0 & 0x1FFFF) * 32 + flane];
        uint2 v1 = xb2[(size_t)(p1 & 0x1FFFF) * 32 + flane];
        uint2 v2 = xb2[(size_t)(p2 & 0x1FFFF) * 32 + flane];
        uint2 v3 = xb2[(size_t)(p3 & 0x1FFFF) * 32 + flane];
        float w0 = UNPACK_W(p0);
        float w1 = UNPACK_W(p1);
        float w2 = UNPACK_W(p2);
        float w3 = UNPACK_W(p3);
        BF16_FMA(a0, v0, w0);
        BF16_FMA(a1, v1, w1);
        BF16_FMA(a2, v2, w2);
        BF16_FMA(a3, v3, w3);
    }
    for (; j + 2 < end; j += 4) {
        unsigned p0 = col_w[j];
        unsigned p1 = col_w[j + 2];
        uint2 v0 = xb2[(size_t)(p0 & 0x1FFFF) * 32 + flane];
        uint2 v1 = xb2[(size_t)(p1 & 0x1FFFF) * 32 + flane];
        float w0 = UNPACK_W(p0);
        float w1 = UNPACK_W(p1);
        BF16_FMA(a0, v0, w0);
        BF16_FMA(a1, v1, w1);
    }
    if (j < end) {
        unsigned p = col_w[j];
        uint2 v = xb2[(size_t)(p & 0x1FFFF) * 32 + flane];
        float wv = UNPACK_W(p);
        BF16_FMA(a0, v, wv);
    }
#undef BF16_FMA
#undef UNPACK_W

    float4 acc;
    acc.x = (a0.x + a1.x) + (a2.x + a3.x);
    acc.y = (a0.y + a1.y) + (a2.y + a3.y);
    acc.z = (a0.z + a1.z) + (a2.z + a3.z);
    acc.w = (a0.w + a1.w) + (a2.w + a3.w);

    acc.x += __shfl_xor(acc.x, 32);
    acc.y += __shfl_xor(acc.y, 32);
    acc.z += __shfl_xor(acc.z, 32);
    acc.w += __shfl_xor(acc.w, 32);

    if (half == 0) {
        long long base = (long long)row * 32 + flane;
        float4 xv = ((const float4*)x)[base];
        float4 x0v = make_float4(0.f, 0.f, 0.f, 0.f);
        if (src != 0.0f)                           // uniform branch; bench src=0
            x0v = ((const float4*)x0)[base];
        float xs[4]  = {xv.x, xv.y, xv.z, xv.w};
        float zs[4]  = {x0v.x, x0v.y, x0v.z, x0v.w};
        float as[4]  = {acc.x, acc.y, acc.z, acc.w};
        float os[4];
#pragma unroll
        for (int k = 0; k < 4; ++k) {
            float reaction = -(xs[k] - 1.0f) * xs[k];
            float st = fminf(fmaxf(src * zs[k], -1.0f), 1.0f);
            os[k] = as[k] - alpha * xs[k] + beta * reaction + st * 0.1f;
        }
        ((float4*)out)[base] = make_float4(os[0], os[1], os[2], os[3]);
    }
}

// fp32-x fallback gather (xb unavailable) -- same 4B col_w format.
__global__ void gather_f32_kernel(const float* __restrict__ x,
                                  const float* __restrict__ x0,
                                  const int* __restrict__ off,
                                  const int* __restrict__ bstart2,
                                  const unsigned* __restrict__ col_w,
                                  const float* __restrict__ alpha_p,
                                  const float* __restrict__ beta_p,
                                  const float* __restrict__ src_p,
                                  float* __restrict__ out, int N) {
    const float alpha = sigmoid_f(alpha_p[0]) * 0.1f;
    const float beta  = sigmoid_f(beta_p[0]) * 0.1f;
    const float src   = src_p[0];

    int gtid = blockIdx.x * blockDim.x + threadIdx.x;
    int row  = gtid >> 6;
    if (row >= N) return;
    int lane  = threadIdx.x & 63;
    int half  = lane >> 5;
    int flane = lane & 31;

    int start = ((row & 127) == 0) ? bstart2[row >> 7] : off[row - 1];
    int end   = off[row];

    const float4* x4 = (const float4*)x;
    float4 a0 = make_float4(0.f, 0.f, 0.f, 0.f);
    float4 a1 = make_float4(0.f, 0.f, 0.f, 0.f);

    int j = start + half;
    for (; j + 2 < end; j += 4) {
        unsigned p0 = col_w[j];
        unsigned p1 = col_w[j + 2];
        float4 v0 = x4[(long long)(p0 & 0x1FFFF) * 32 + flane];
        float4 v1 = x4[(long long)(p1 & 0x1FFFF) * 32 + flane];
        float w0 = __uint_as_float((p0 >> 17) << 16);
        float w1 = __uint_as_float((p1 >> 17) << 16);
        a0.x += w0 * v0.x; a0.y += w0 * v0.y; a0.z += w0 * v0.z; a0.w += w0 * v0.w;
        a1.x += w1 * v1.x; a1.y += w1 * v1.y; a1.z += w1 * v1.z; a1.w += w1 * v1.w;
    }
    if (j < end) {
        unsigned p = col_w[j];
        float4 v = x4[(long long)(p & 0x1FFFF) * 32 + flane];
        float wv = __uint_as_float((p >> 17) << 16);
        a0.x += wv * v.x; a0.y += wv * v.y; a0.z += wv * v.z; a0.w += wv * v.w;
    }
    float4 acc;
    acc.x = a0.x + a1.x; acc.y = a0.y + a1.y;
    acc.z = a0.z + a1.z; acc.w = a0.w + a1.w;

    acc.x += __shfl_xor(acc.x, 32);
    acc.y += __shfl_xor(acc.y, 32);
    acc.z += __shfl_xor(acc.z, 32);
    acc.w += __shfl_xor(acc.w, 32);

    if (half == 0) {
        long long base = (long long)row * 32 + flane;
        float4 xv  = x4[base];
        float4 x0v = make_float4(0.f, 0.f, 0.f, 0.f);
        if (src != 0.0f)
            x0v = ((const float4*)x0)[base];
        float xs[4]  = {xv.x, xv.y, xv.z, xv.w};
        float zs[4]  = {x0v.x, x0v.y, x0v.z, x0v.w};
        float as[4]  = {acc.x, acc.y, acc.z, acc.w};
        float os[4];
#pragma unroll
        for (int k = 0; k < 4; ++k) {
            float reaction = -(xs[k] - 1.0f) * xs[k];
            float st = fminf(fmaxf(src * zs[k], -1.0f), 1.0f);
            os[k] = as[k] - alpha * xs[k] + beta * reaction + st * 0.1f;
        }
        ((float4*)out)[base] = make_float4(os[0], os[1], os[2], os[3]);
    }
}

extern "C" void kernel_launch(void* const* d_in, const int* in_sizes, int n_in,
                              void* d_out, int out_size, void* d_ws, size_t ws_size,
                              hipStream_t stream) {
    const float* x   = (const float*)d_in[1];
    const int*   ei  = (const int*)d_in[2];
    const float* ew  = (const float*)d_in[3];
    const float* x0  = (const float*)d_in[4];
    const float* alp = (const float*)d_in[5];
    const float* bet = (const float*)d_in[6];
    const float* src = (const float*)d_in[7];
    float* out = (float*)d_out;

    const int E = in_sizes[3];
    const int N = out_size / D_FEAT;
    const int* rows = ei;
    const int* cols = ei + E;

    const int NB   = (N + RPB - 1) / RPB;        // 782
    const int nBlk = (E + EPB - 1) / EPB;        // 782 (<= NBLK_MAX)

    // ws: off + bstart2 + col_w (E*4) + xb (N*D*2)
    char* ws = (char*)d_ws;
    char* ws_end = (char*)d_ws + ws_size;
    int*      off     = (int*)ws;      ws += ((size_t)N * 4 + 15) & ~15ull;
    int*      bstart2 = (int*)ws;      ws += ((size_t)NB * 4 + 15) & ~15ull;
    unsigned* col_w   = (unsigned*)ws; ws += ((size_t)E * 4 + 15) & ~15ull;

    // Arena + directory + blkBase + cursors live in d_out (dead until gather).
    char* ob = (char*)d_out;
    int2*     arena   = (int2*)ob;       ob += ((size_t)E * 8 + 15) & ~15ull;
    unsigned* dir     = (unsigned*)ob;   ob += ((size_t)NB * nBlk * 4 + 15) & ~15ull;
    int*      blkBase = (int*)ob;        ob += ((size_t)nBlk * 4 + 15) & ~15ull;
    int*      cursors = (int*)ob;        ob += 16;
    if (ob > (char*)d_out + out_size) {
        // fallback: carve from ws (plenty at this problem size)
        arena   = (int2*)ws;     ws += ((size_t)E * 8 + 15) & ~15ull;
        dir     = (unsigned*)ws; ws += ((size_t)NB * nBlk * 4 + 15) & ~15ull;
        blkBase = (int*)ws;      ws += ((size_t)nBlk * 4 + 15) & ~15ull;
        cursors = (int*)ws;      ws += 16;
    }

    // bf16 x table, if workspace permits.
    unsigned short* xb = nullptr;
    size_t xb_bytes = ((size_t)N * D_FEAT * 2 + 15) & ~15ull;
    if (ws + xb_bytes <= ws_end) {
        xb = (unsigned short*)ws;  ws += xb_bytes;
    }

    {
        int n8 = (N * D_FEAT) / 8;
        int grid = xb ? (n8 + 255) / 256 : 1;
        cvt_kernel<<<grid, 256, 0, stream>>>(x, xb, n8, cursors);
    }
    place_kernel<<<nBlk, 256, 0, stream>>>(rows, cols, ew, alp,
                                           &cursors[0], arena, dir, blkBase,
                                           E, NB, nBlk);
    sort_kernel<<<NB, 256, 0, stream>>>(arena, dir, blkBase, nBlk,
                                        col_w, &cursors[1], off, bstart2, N, NB);
    {
        long long threads = (long long)N * 64;
        int grid = (int)((threads + 255) / 256);
        if (xb)
            gather_bf16_kernel<<<grid, 256, 0, stream>>>(x, xb, x0, off, bstart2,
                                                         col_w, alp, bet, src, out, N);
        else
            gather_f32_kernel<<<grid, 256, 0, stream>>>(x, x0, off, bstart2,
                                                        col_w, alp, bet, src, out, N);
    }
}